// Round 2
// baseline (308.643 us; speedup 1.0000x reference)
//
#include <hip/hip_runtime.h>
#include <math.h>

// Problem constants (fixed by setup_inputs)
#define BATCH 4
#define NHEAD 8
#define HD 24          // head dim (channels per head)
#define CH 192         // total channels
#define HW 16384       // h*w
#define NSPLIT 32      // hw splits (one block per split, 2 sub-chunks each)
#define SUBS 2
#define CHUNK 256      // columns per sub-chunk
#define LSTR 264       // 256 + 8 pad: breaks power-of-2 row stride (2-way max aliasing)

// ws layout (floats):
//   sqq: [768][32]        off 0
//   sqk: [768][32]        off 24576
//   Sp:  [32][576][32]    off 49152
//   Mt:  [4][192][192]    off 638976   ([b][c][o])
// total 786432 floats = 3.1 MB
#define OFF_SQK 24576
#define OFF_S   49152
#define OFF_M   638976

__device__ __forceinline__ float dot4(const float4& a, const float4& b) {
    return fmaf(a.x, b.x, fmaf(a.y, b.y, fmaf(a.z, b.z, a.w * b.w)));
}

// ---------------------------------------------------------------------------
// Kernel A: per (b*head, hw-split): raw 24x24 Gram partials + q/k row sumsq
// folded into the Gram loop (no shuffle trees). grid (32, 32), block 256.
// ---------------------------------------------------------------------------
__global__ __launch_bounds__(256) void kA(const float* __restrict__ q,
                                          const float* __restrict__ k,
                                          float* __restrict__ ws) {
    __shared__ float qs[HD * LSTR];
    __shared__ float ks[HD * LSTR];
    __shared__ float rsq[HD * 4], rsk[HD * 4];

    const int bh   = blockIdx.x;   // 0..31
    const int sp   = blockIdx.y;   // 0..31
    const int t    = threadIdx.x;
    const int lane = t & 63;
    const int wave = t >> 6;       // 0..3
    const int i0   = (lane >> 3) * 3;
    const int j0   = (lane & 7) * 3;
    const int n0   = wave * 64;

    float4 acc[3][3];
    #pragma unroll
    for (int a = 0; a < 3; ++a)
        #pragma unroll
        for (int bb = 0; bb < 3; ++bb) acc[a][bb] = make_float4(0.f, 0.f, 0.f, 0.f);
    float sqa[3] = {0.f, 0.f, 0.f}, ska[3] = {0.f, 0.f, 0.f};

    for (int sc = 0; sc < SUBS; ++sc) {
        const float* qb = q + (size_t)bh * HD * HW + sp * (SUBS * CHUNK) + sc * CHUNK;
        const float* kb = k + (size_t)bh * HD * HW + sp * (SUBS * CHUNK) + sc * CHUNK;

        if (sc) __syncthreads();   // previous compute reads done before overwrite
        #pragma unroll
        for (int it = 0; it < 6; ++it) {
            const int row = it * 4 + wave;     // 0..23, each once
            const int col = lane * 4;
            float4 qv = *(const float4*)(qb + (size_t)row * HW + col);
            float4 kv = *(const float4*)(kb + (size_t)row * HW + col);
            *(float4*)&qs[row * LSTR + col] = qv;
            *(float4*)&ks[row * LSTR + col] = kv;
        }
        __syncthreads();

        for (int n = n0; n < n0 + 64; n += 4) {
            float4 qa[3], kv[3];
            #pragma unroll
            for (int a = 0; a < 3; ++a) qa[a] = *(float4*)&qs[(i0 + a) * LSTR + n];
            #pragma unroll
            for (int bb = 0; bb < 3; ++bb) kv[bb] = *(float4*)&ks[(j0 + bb) * LSTR + n];
            if (j0 == 0) {
                #pragma unroll
                for (int a = 0; a < 3; ++a) sqa[a] += dot4(qa[a], qa[a]);
            }
            if (i0 == 0) {
                #pragma unroll
                for (int bb = 0; bb < 3; ++bb) ska[bb] += dot4(kv[bb], kv[bb]);
            }
            #pragma unroll
            for (int a = 0; a < 3; ++a)
                #pragma unroll
                for (int bb = 0; bb < 3; ++bb) {
                    acc[a][bb].x = fmaf(qa[a].x, kv[bb].x, acc[a][bb].x);
                    acc[a][bb].y = fmaf(qa[a].y, kv[bb].y, acc[a][bb].y);
                    acc[a][bb].z = fmaf(qa[a].z, kv[bb].z, acc[a][bb].z);
                    acc[a][bb].w = fmaf(qa[a].w, kv[bb].w, acc[a][bb].w);
                }
        }
    }

    __syncthreads();               // all LDS reads done; reuse qs as reducer
    if (j0 == 0) {
        #pragma unroll
        for (int a = 0; a < 3; ++a) rsq[(i0 + a) * 4 + wave] = sqa[a];
    }
    if (i0 == 0) {
        #pragma unroll
        for (int bb = 0; bb < 3; ++bb) rsk[(j0 + bb) * 4 + wave] = ska[bb];
    }
    float* red = qs;               // [576][4]
    #pragma unroll
    for (int a = 0; a < 3; ++a)
        #pragma unroll
        for (int bb = 0; bb < 3; ++bb) {
            float s = acc[a][bb].x + acc[a][bb].y + acc[a][bb].z + acc[a][bb].w;
            red[((i0 + a) * HD + (j0 + bb)) * 4 + wave] = s;
        }
    __syncthreads();

    float* sqq = ws;
    float* sqk = ws + OFF_SQK;
    float* Sp  = ws + OFF_S;
    for (int e = t; e < HD * HD; e += 256) {
        float v = red[e * 4] + red[e * 4 + 1] + red[e * 4 + 2] + red[e * 4 + 3];
        Sp[((size_t)bh * (HD * HD) + e) * NSPLIT + sp] = v;
    }
    if (t < 2 * HD) {
        const int row = (t < HD) ? t : t - HD;
        const float* r = (t < HD) ? &rsq[row * 4] : &rsk[row * 4];
        float s = r[0] + r[1] + r[2] + r[3];
        float* dst = (t < HD) ? sqq : sqk;
        dst[(bh * HD + row) * NSPLIT + sp] = s;
    }
}

// ---------------------------------------------------------------------------
// Kernel B: per (b,head): finalize norms, logits, softmax, fold
// proj_w * attn * diag(kinv) into M' [b][c][o]. grid 32, block 256.
// ---------------------------------------------------------------------------
__global__ __launch_bounds__(256) void kB(const float* __restrict__ scale,
                                          const float* __restrict__ w,
                                          float* __restrict__ ws) {
    const int bh = blockIdx.x;
    const int b  = bh >> 3;
    const int h  = bh & 7;
    const int t  = threadIdx.x;

    __shared__ float qinv[HD], kinv[HD];
    __shared__ float A[HD * HD];
    __shared__ float wl[CH * HD];

    const float* sqq = ws;
    const float* sqk = ws + OFF_SQK;
    const float* Sp  = ws + OFF_S;
    float* Mt = ws + OFF_M;

    if (t < 2 * HD) {
        const float* src = (t < HD) ? (sqq + (bh * HD + t) * NSPLIT)
                                    : (sqk + (bh * HD + (t - HD)) * NSPLIT);
        float4 s4 = make_float4(0.f, 0.f, 0.f, 0.f);
        #pragma unroll
        for (int i = 0; i < NSPLIT / 4; ++i) {
            float4 v = *(const float4*)(src + i * 4);
            s4.x += v.x; s4.y += v.y; s4.z += v.z; s4.w += v.w;
        }
        float s = s4.x + s4.y + s4.z + s4.w;
        float inv = 1.0f / fmaxf(sqrtf(s), 1e-12f);
        if (t < HD) qinv[t] = inv; else kinv[t - HD] = inv;
    }
    for (int idx = t; idx < CH * HD; idx += 256) {
        int o = idx / HD, dd = idx % HD;
        wl[idx] = w[o * CH + h * HD + dd];
    }
    __syncthreads();

    const float sc = scale[h];
    for (int e = t; e < HD * HD; e += 256) {
        const float* sp = Sp + ((size_t)bh * (HD * HD) + e) * NSPLIT;
        float4 s4 = make_float4(0.f, 0.f, 0.f, 0.f);
        #pragma unroll
        for (int i = 0; i < NSPLIT / 4; ++i) {
            float4 v = *(const float4*)(sp + i * 4);
            s4.x += v.x; s4.y += v.y; s4.z += v.z; s4.w += v.w;
        }
        float s = s4.x + s4.y + s4.z + s4.w;
        A[e] = s * qinv[e / HD] * kinv[e % HD] * sc;
    }
    __syncthreads();

    if (t < HD) {   // softmax along j for row t
        float m = -1e30f;
        for (int j = 0; j < HD; ++j) m = fmaxf(m, A[t * HD + j]);
        float sum = 0.f;
        for (int j = 0; j < HD; ++j) {
            float v = expf(A[t * HD + j] - m);
            A[t * HD + j] = v;
            sum += v;
        }
        float r = 1.0f / sum;
        for (int j = 0; j < HD; ++j) A[t * HD + j] *= r;
    }
    __syncthreads();

    // M'[b][h*24+j][o] = (sum_i w[o, h*24+i] * A[i][j]) * kinv[j]
    for (int idx = t; idx < CH * HD; idx += 256) {
        int o = idx / HD, j = idx % HD;
        float v = 0.f;
        #pragma unroll
        for (int i = 0; i < HD; ++i) v = fmaf(wl[o * HD + i], A[i * HD + j], v);
        Mt[(size_t)b * CH * CH + (h * HD + j) * CH + o] = v * kinv[j];
    }
}

// ---------------------------------------------------------------------------
// Kernel C: out[b][o][n] = sum_c M'[b][c][o] * k[b][c][n]
// Tile 64 o x 256 n, micro 8x8, c-chunks of 16 staged per-chunk (LDS 20.5 KB
// -> 4 blocks/CU vs 2 with a resident 48 KB M tile).
// grid (64, 3, 4), block 256.
// ---------------------------------------------------------------------------
#define OTILE 64
#define NTILE 256
#define CCH   16

__device__ __forceinline__ void fma4(float4& a, float s, const float4& v) {
    a.x = fmaf(s, v.x, a.x); a.y = fmaf(s, v.y, a.y);
    a.z = fmaf(s, v.z, a.z); a.w = fmaf(s, v.w, a.w);
}

__global__ __launch_bounds__(256, 4) void kC(const float* __restrict__ k,
                                             const float* __restrict__ ws,
                                             float* __restrict__ out) {
    __shared__ float Ms[CCH * OTILE];   // 4 KB
    __shared__ float kt[CCH * NTILE];   // 16 KB

    const int t  = threadIdx.x;
    const int nb = blockIdx.x * NTILE;
    const int ob = blockIdx.y * OTILE;
    const int b  = blockIdx.z;

    const float* Mt = ws + OFF_M + (size_t)b * CH * CH;
    const float* kb = k + (size_t)b * CH * HW;
    float* op = out + (size_t)b * CH * HW;

    const int po = t >> 5;   // 0..7
    const int pn = t & 31;   // 0..31

    float4 acc[8][2];
    #pragma unroll
    for (int a = 0; a < 8; ++a) { acc[a][0] = make_float4(0,0,0,0); acc[a][1] = make_float4(0,0,0,0); }

    for (int c0 = 0; c0 < CH; c0 += CCH) {
        if (c0) __syncthreads();   // previous compute reads done before overwrite
        {   // Ms: 16x64 floats, one float4 per thread
            const int cc = t >> 4, o4 = (t & 15) * 4;
            *(float4*)&Ms[cc * OTILE + o4] =
                *(const float4*)(Mt + (size_t)(c0 + cc) * CH + ob + o4);
        }
        #pragma unroll
        for (int it = 0; it < 4; ++it) {   // kt: 16x256 floats
            const int idx = it * 256 + t;
            const int cc = idx >> 6, col = (idx & 63) * 4;
            *(float4*)&kt[cc * NTILE + col] =
                *(const float4*)(kb + (size_t)(c0 + cc) * HW + nb + col);
        }
        __syncthreads();
        #pragma unroll
        for (int cc = 0; cc < CCH; ++cc) {
            float4 m0 = *(float4*)&Ms[cc * OTILE + po * 4];
            float4 m1 = *(float4*)&Ms[cc * OTILE + 32 + po * 4];
            float4 k0 = *(float4*)&kt[cc * NTILE + pn * 4];
            float4 k1 = *(float4*)&kt[cc * NTILE + 128 + pn * 4];
            fma4(acc[0][0], m0.x, k0); fma4(acc[0][1], m0.x, k1);
            fma4(acc[1][0], m0.y, k0); fma4(acc[1][1], m0.y, k1);
            fma4(acc[2][0], m0.z, k0); fma4(acc[2][1], m0.z, k1);
            fma4(acc[3][0], m0.w, k0); fma4(acc[3][1], m0.w, k1);
            fma4(acc[4][0], m1.x, k0); fma4(acc[4][1], m1.x, k1);
            fma4(acc[5][0], m1.y, k0); fma4(acc[5][1], m1.y, k1);
            fma4(acc[6][0], m1.z, k0); fma4(acc[6][1], m1.z, k1);
            fma4(acc[7][0], m1.w, k0); fma4(acc[7][1], m1.w, k1);
        }
    }

    #pragma unroll
    for (int a = 0; a < 8; ++a) {
        int o = ob + ((a < 4) ? (po * 4 + a) : (32 + po * 4 + (a - 4)));
        *(float4*)(op + (size_t)o * HW + nb + pn * 4)       = acc[a][0];
        *(float4*)(op + (size_t)o * HW + nb + 128 + pn * 4) = acc[a][1];
    }
}

extern "C" void kernel_launch(void* const* d_in, const int* in_sizes, int n_in,
                              void* d_out, int out_size, void* d_ws, size_t ws_size,
                              hipStream_t stream) {
    const float* in1   = (const float*)d_in[0];
    const float* in2   = (const float*)d_in[1];
    const float* scale = (const float*)d_in[2];
    const float* projw = (const float*)d_in[3];
    float* ws  = (float*)d_ws;   // needs 3.1 MB
    float* out = (float*)d_out;

    kA<<<dim3(32, NSPLIT), 256, 0, stream>>>(in1, in2, ws);
    kB<<<32, 256, 0, stream>>>(scale, projw, ws);
    kC<<<dim3(HW / NTILE, CH / OTILE, BATCH), 256, 0, stream>>>(in2, ws, out);
}

// Round 3
// 215.595 us; speedup vs baseline: 1.4316x; 1.4316x over previous
//
#include <hip/hip_runtime.h>
#include <hip/hip_bf16.h>
#include <math.h>

// Problem constants (fixed by setup_inputs)
#define BATCH 4
#define NHEAD 8
#define HD 24          // head dim (channels per head)
#define CH 192         // total channels
#define HW 16384       // h*w
#define NSPLIT 32      // hw splits for the Gram partials

// ws layout (floats):
//   sqq:  [768][32]                 off 0
//   sqk:  [768][32]                 off 24576
//   Sp:   [32][576][32]             off 49152
//   Mo:   ushort[4][192][192]       off 638976   ([b][o][c] bf16)
//   KbfT: ushort[4][16384][192]     off 712704   ([b][n][c] bf16)
// total 7,004,160 floats = 28.0 MB
#define OFF_SQK 24576
#define OFF_S   49152
#define OFF_MO  638976
#define OFF_KT  712704

typedef __attribute__((ext_vector_type(8))) short bf16x8;
typedef __attribute__((ext_vector_type(4))) float f32x4;

__device__ __forceinline__ float dot4(const float4& a, const float4& b) {
    return fmaf(a.x, b.x, fmaf(a.y, b.y, fmaf(a.z, b.z, a.w * b.w)));
}

__device__ __forceinline__ unsigned short bf16rne(float x) {
    union { float f; unsigned u; } v; v.f = x;
    unsigned u = v.u;
    unsigned r = (u + 0x7FFFu + ((u >> 16) & 1u)) >> 16;
    return (unsigned short)r;
}

// pack 8 fp32 -> 8 bf16 (RNE) using the packed-cvt HW path
__device__ __forceinline__ bf16x8 pack8(const float4& a, const float4& b) {
    union { __hip_bfloat162 h; unsigned u; } c0, c1, c2, c3;
    c0.h = __float22bfloat162_rn(float2{a.x, a.y});
    c1.h = __float22bfloat162_rn(float2{a.z, a.w});
    c2.h = __float22bfloat162_rn(float2{b.x, b.y});
    c3.h = __float22bfloat162_rn(float2{b.z, b.w});
    union { unsigned u[4]; bf16x8 v; } r;
    r.u[0] = c0.u; r.u[1] = c1.u; r.u[2] = c2.u; r.u[3] = c3.u;
    return r.v;
}

// ---------------------------------------------------------------------------
// Kernel A: streaming MFMA Gram. Per (bh, hw-split): each wave handles 128 hw
// columns; per 32-step: load q/k rows into A/B bf16 frags (24 rows padded to
// 2x16), 4 MFMAs, register sumsq, and emit K^T bf16. No data LDS, no barriers
// in the main loop. grid (32, 32), block 256.
// ---------------------------------------------------------------------------
__global__ __launch_bounds__(256) void kA(const float* __restrict__ q,
                                          const float* __restrict__ k,
                                          float* __restrict__ ws,
                                          unsigned short* __restrict__ kbfT) {
    const int bh   = blockIdx.x;   // 0..31
    const int sp   = blockIdx.y;   // 0..31
    const int t    = threadIdx.x;
    const int lane = t & 63;
    const int wave = t >> 6;
    const int nl   = lane & 15;    // m for A, n for B
    const int quad = lane >> 4;    // k-group
    const bool hiv = nl < 8;       // rows 16..23 valid
    const int b    = bh >> 3;
    const int h    = bh & 7;

    const float* qb = q + (size_t)bh * HD * HW;
    const float* kb = k + (size_t)bh * HD * HW;
    unsigned short* kT = kbfT + (size_t)b * HW * CH + h * HD;

    f32x4 acc[2][2];
    #pragma unroll
    for (int mg = 0; mg < 2; ++mg)
        #pragma unroll
        for (int ng = 0; ng < 2; ++ng) acc[mg][ng] = (f32x4)(0.f);
    float sql = 0.f, sqh = 0.f, skl = 0.f, skh = 0.f;

    const int hwbase = sp * 512 + wave * 128;
    const float4 z4 = make_float4(0.f, 0.f, 0.f, 0.f);

    #pragma unroll 2
    for (int s = 0; s < 4; ++s) {
        const int off = hwbase + s * 32 + quad * 8;
        const float* qr = qb + (size_t)nl * HW + off;
        const float* kr = kb + (size_t)nl * HW + off;
        const float* qr2 = qb + (size_t)(16 + nl) * HW + off;
        const float* kr2 = kb + (size_t)(16 + nl) * HW + off;

        float4 q0 = *(const float4*)qr,  q1 = *(const float4*)(qr + 4);
        float4 k0 = *(const float4*)kr,  k1 = *(const float4*)(kr + 4);
        float4 q2 = hiv ? *(const float4*)qr2 : z4;
        float4 q3 = hiv ? *(const float4*)(qr2 + 4) : z4;
        float4 k2 = hiv ? *(const float4*)kr2 : z4;
        float4 k3 = hiv ? *(const float4*)(kr2 + 4) : z4;

        sql += dot4(q0, q0) + dot4(q1, q1);
        sqh += dot4(q2, q2) + dot4(q3, q3);
        skl += dot4(k0, k0) + dot4(k1, k1);
        skh += dot4(k2, k2) + dot4(k3, k3);

        bf16x8 aql = pack8(q0, q1), aqh = pack8(q2, q3);
        bf16x8 bkl = pack8(k0, k1), bkh = pack8(k2, k3);

        acc[0][0] = __builtin_amdgcn_mfma_f32_16x16x32_bf16(aql, bkl, acc[0][0], 0, 0, 0);
        acc[0][1] = __builtin_amdgcn_mfma_f32_16x16x32_bf16(aql, bkh, acc[0][1], 0, 0, 0);
        acc[1][0] = __builtin_amdgcn_mfma_f32_16x16x32_bf16(aqh, bkl, acc[1][0], 0, 0, 0);
        acc[1][1] = __builtin_amdgcn_mfma_f32_16x16x32_bf16(aqh, bkh, acc[1][1], 0, 0, 0);

        // emit K^T bf16: element j of the k-frags is hw = off+j, channel nl / 16+nl
        #pragma unroll
        for (int j = 0; j < 8; ++j)
            kT[(size_t)(off + j) * CH + nl] = (unsigned short)bkl[j];
        if (hiv) {
            #pragma unroll
            for (int j = 0; j < 8; ++j)
                kT[(size_t)(off + j) * CH + 16 + nl] = (unsigned short)bkh[j];
        }
    }

    // ---- reduce sumsq across the 4 quads holding the same row ----
    sql += __shfl_xor(sql, 16, 64); sql += __shfl_xor(sql, 32, 64);
    sqh += __shfl_xor(sqh, 16, 64); sqh += __shfl_xor(sqh, 32, 64);
    skl += __shfl_xor(skl, 16, 64); skl += __shfl_xor(skl, 32, 64);
    skh += __shfl_xor(skh, 16, 64); skh += __shfl_xor(skh, 32, 64);

    __shared__ float red[4][576];
    __shared__ float rq[4][24], rk[4][24];
    if (lane < 16) { rq[wave][lane] = sql; rk[wave][lane] = skl; }
    if (lane < 8)  { rq[wave][16 + lane] = sqh; rk[wave][16 + lane] = skh; }

    // ---- scatter valid Gram entries (C/D: col=lane&15, row=quad*4+reg) ----
    #pragma unroll
    for (int mg = 0; mg < 2; ++mg)
        #pragma unroll
        for (int ng = 0; ng < 2; ++ng)
            #pragma unroll
            for (int r = 0; r < 4; ++r) {
                int i = mg * 16 + quad * 4 + r;
                int j = ng * 16 + nl;
                if (i < 24 && j < 24) red[wave][i * 24 + j] = acc[mg][ng][r];
            }
    __syncthreads();

    float* sqq = ws;
    float* sqk = ws + OFF_SQK;
    float* Sp  = ws + OFF_S;
    for (int e = t; e < 576; e += 256) {
        float v = red[0][e] + red[1][e] + red[2][e] + red[3][e];
        Sp[((size_t)bh * 576 + e) * NSPLIT + sp] = v;
    }
    if (t < 48) {
        int row = (t < 24) ? t : t - 24;
        float s;
        if (t < 24) s = rq[0][row] + rq[1][row] + rq[2][row] + rq[3][row];
        else        s = rk[0][row] + rk[1][row] + rk[2][row] + rk[3][row];
        float* dst = (t < 24) ? sqq : sqk;
        dst[(bh * HD + row) * NSPLIT + sp] = s;
    }
}

// ---------------------------------------------------------------------------
// Kernel B: per (b,head): finalize norms, logits, softmax, fold
// proj_w * attn * diag(kinv) into Mo[b][o][c] (bf16). grid 32, block 256.
// ---------------------------------------------------------------------------
__global__ __launch_bounds__(256) void kB(const float* __restrict__ scale,
                                          const float* __restrict__ w,
                                          float* __restrict__ ws,
                                          unsigned short* __restrict__ Mo) {
    const int bh = blockIdx.x;
    const int b  = bh >> 3;
    const int h  = bh & 7;
    const int t  = threadIdx.x;

    __shared__ float qinv[HD], kinv[HD];
    __shared__ float A[HD * HD];
    __shared__ float wl[CH * HD];

    const float* sqq = ws;
    const float* sqk = ws + OFF_SQK;
    const float* Sp  = ws + OFF_S;

    if (t < 2 * HD) {
        const float* src = (t < HD) ? (sqq + (bh * HD + t) * NSPLIT)
                                    : (sqk + (bh * HD + (t - HD)) * NSPLIT);
        float4 s4 = make_float4(0.f, 0.f, 0.f, 0.f);
        #pragma unroll
        for (int i = 0; i < NSPLIT / 4; ++i) {
            float4 v = *(const float4*)(src + i * 4);
            s4.x += v.x; s4.y += v.y; s4.z += v.z; s4.w += v.w;
        }
        float s = s4.x + s4.y + s4.z + s4.w;
        float inv = 1.0f / fmaxf(sqrtf(s), 1e-12f);
        if (t < HD) qinv[t] = inv; else kinv[t - HD] = inv;
    }
    for (int idx = t; idx < CH * HD; idx += 256) {
        int o = idx / HD, dd = idx % HD;
        wl[idx] = w[o * CH + h * HD + dd];
    }
    __syncthreads();

    const float sc = scale[h];
    for (int e = t; e < HD * HD; e += 256) {
        const float* sp = Sp + ((size_t)bh * 576 + e) * NSPLIT;
        float4 s4 = make_float4(0.f, 0.f, 0.f, 0.f);
        #pragma unroll
        for (int i = 0; i < NSPLIT / 4; ++i) {
            float4 v = *(const float4*)(sp + i * 4);
            s4.x += v.x; s4.y += v.y; s4.z += v.z; s4.w += v.w;
        }
        float s = s4.x + s4.y + s4.z + s4.w;
        A[e] = s * qinv[e / HD] * kinv[e % HD] * sc;
    }
    __syncthreads();

    if (t < HD) {   // softmax along j for row t
        float m = -1e30f;
        for (int j = 0; j < HD; ++j) m = fmaxf(m, A[t * HD + j]);
        float sum = 0.f;
        for (int j = 0; j < HD; ++j) {
            float v = expf(A[t * HD + j] - m);
            A[t * HD + j] = v;
            sum += v;
        }
        float r = 1.0f / sum;
        for (int j = 0; j < HD; ++j) A[t * HD + j] *= r;
    }
    __syncthreads();

    // Mo[b][o][h*24+j] = (sum_i w[o, h*24+i] * attn[i][j]) * kinv[j]   (bf16)
    for (int idx = t; idx < CH * HD; idx += 256) {
        int o = idx / HD, j = idx % HD;
        float v = 0.f;
        #pragma unroll
        for (int i = 0; i < HD; ++i) v = fmaf(wl[o * HD + i], A[i * HD + j], v);
        Mo[(size_t)b * CH * CH + (size_t)o * CH + h * HD + j] = bf16rne(v * kinv[j]);
    }
}

// ---------------------------------------------------------------------------
// Kernel C: out[b][o][n] = sum_c Mo[b][o][c] * KbfT[b][n][c]  via MFMA.
// No LDS: A-frags from Mo (c-contiguous), B-frags from KbfT (c-contiguous).
// Per wave: one 16-o tile x 128 n (8 tiles), 6 K-steps of 32.
// grid (128, 3, 4), block 256.
// ---------------------------------------------------------------------------
__global__ __launch_bounds__(256) void kC(const unsigned short* __restrict__ kbfT,
                                          const unsigned short* __restrict__ Mo,
                                          float* __restrict__ out) {
    const int t    = threadIdx.x;
    const int lane = t & 63;
    const int wave = t >> 6;
    const int nl   = lane & 15;
    const int quad = lane >> 4;

    const int nb = blockIdx.x * 128;
    const int ob = blockIdx.y * 64 + wave * 16;
    const int b  = blockIdx.z;

    const unsigned short* Arow = Mo + (size_t)b * CH * CH + (size_t)(ob + nl) * CH;
    const unsigned short* Kb   = kbfT + (size_t)b * HW * CH;

    f32x4 acc[8];
    #pragma unroll
    for (int nt = 0; nt < 8; ++nt) acc[nt] = (f32x4)(0.f);

    #pragma unroll 2
    for (int c0 = 0; c0 < CH; c0 += 32) {
        bf16x8 af = *(const bf16x8*)(Arow + c0 + quad * 8);
        #pragma unroll
        for (int nt = 0; nt < 8; ++nt) {
            bf16x8 bfv = *(const bf16x8*)(Kb + (size_t)(nb + nt * 16 + nl) * CH + c0 + quad * 8);
            acc[nt] = __builtin_amdgcn_mfma_f32_16x16x32_bf16(af, bfv, acc[nt], 0, 0, 0);
        }
    }

    float* op = out + (size_t)b * CH * HW;
    #pragma unroll
    for (int nt = 0; nt < 8; ++nt) {
        const int n = nb + nt * 16 + nl;
        #pragma unroll
        for (int r = 0; r < 4; ++r) {
            const int o = ob + quad * 4 + r;
            op[(size_t)o * HW + n] = acc[nt][r];
        }
    }
}

extern "C" void kernel_launch(void* const* d_in, const int* in_sizes, int n_in,
                              void* d_out, int out_size, void* d_ws, size_t ws_size,
                              hipStream_t stream) {
    const float* in1   = (const float*)d_in[0];
    const float* in2   = (const float*)d_in[1];
    const float* scale = (const float*)d_in[2];
    const float* projw = (const float*)d_in[3];
    float* ws  = (float*)d_ws;   // needs 28.0 MB
    float* out = (float*)d_out;
    unsigned short* Mo   = (unsigned short*)(ws + OFF_MO);
    unsigned short* kbfT = (unsigned short*)(ws + OFF_KT);

    kA<<<dim3(32, NSPLIT), 256, 0, stream>>>(in1, in2, ws, kbfT);
    kB<<<32, 256, 0, stream>>>(scale, projw, ws, Mo);
    kC<<<dim3(HW / 128, CH / 64, BATCH), 256, 0, stream>>>(kbfT, Mo, out);
}